// Round 2
// baseline (198.555 us; speedup 1.0000x reference)
//
#include <hip/hip_runtime.h>
#include <math.h>

#define B_   16384
#define NP   6
#define SA1  44    // phase-1 A-tile LDS stride (floats), 16B-aligned, 2-way banks
#define SW1  132   // phase-1 W/Y + phase-3 W3 stride
#define SX   100   // X1/X2/Y2 stride
#define SMEMF 19200

__device__ __forceinline__ float gelu_f(float x) {
    return 0.5f * x * (1.0f + erff(x * 0.7071067811865476f));
}

__device__ __forceinline__ float wred64(float v) {
#pragma unroll
    for (int m = 32; m; m >>= 1) v += __shfl_xor(v, m, 64);
    return v;
}

// ---------------- kernel 1: needs + compaction + zero-fill dead rows ----------------
__global__ __launch_bounds__(256) void k_mask(
    const int* __restrict__ mask,
    float* __restrict__ out0, float* __restrict__ out1, float* __restrict__ out2,
    int* __restrict__ counts, int* __restrict__ lists)
{
    int p    = blockIdx.x >> 8;
    int tile = blockIdx.x & 255;
    int row0 = tile * 64;
    int t    = threadIdx.x;
    int src  = p >> 1;                       // 0,0,1,1,2,2
    int tgt  = (0x102021 >> (p * 4)) & 0xF;  // 1,2,0,2,0,1

    __shared__ int s_needs[64];
    if (t < 64) {
        int b  = row0 + t;
        int ms = mask[b * 3 + src];
        int mt = mask[b * 3 + tgt];
        int needs = (ms != 0) && (mt == 0);
        s_needs[t] = needs;
        unsigned long long bal = __ballot(needs);
        int total = __popcll(bal);
        int base = 0;
        if (t == 0 && total) base = atomicAdd(&counts[p], total);
        base = __shfl(base, 0, 64);
        if (needs) {
            int prefix = __popcll(bal & ((1ull << t) - 1ull));
            lists[p * B_ + base + prefix] = b;
        }
    }
    __syncthreads();

    int wave = t >> 6, lane = t & 63;
    float4 z = make_float4(0.f, 0.f, 0.f, 0.f);
    for (int r = wave; r < 64; r += 4) {
        if (!s_needs[r]) {
            size_t rowoff = ((size_t)(p * B_ + row0 + r)) * 256 + lane * 4;
            *(float4*)(out0 + rowoff) = z;
            *(float4*)(out1 + rowoff) = z;
        }
    }
    if (t < 64 && !s_needs[t]) out2[p * B_ + row0 + t] = 0.f;
}

// ---------------- kernel 2: fused MLP over compacted rows ----------------
__global__ __launch_bounds__(256, 2) void k_main(
    const float* __restrict__ mus, const float* __restrict__ logvars,
    const float* __restrict__ hw1, const float* __restrict__ hb1,
    const float* __restrict__ hg1, const float* __restrict__ hbe1,
    const float* __restrict__ hw2, const float* __restrict__ hb2,
    const float* __restrict__ hg2, const float* __restrict__ hbe2,
    const float* __restrict__ hw3, const float* __restrict__ hb3,
    const float* __restrict__ gw1, const float* __restrict__ gb1,
    const float* __restrict__ gg1, const float* __restrict__ gbe1,
    const float* __restrict__ gw2, const float* __restrict__ gb2,
    const int* __restrict__ counts, const int* __restrict__ lists,
    float* __restrict__ out0, float* __restrict__ out1, float* __restrict__ out2)
{
    int p    = blockIdx.x >> 8;
    int tile = blockIdx.x & 255;
    int cnt  = counts[p];
    int start = tile * 64;
    if (start >= cnt) return;
    int nr = min(64, cnt - start);

    __shared__ int   s_rows[64];
    __shared__ float smem[SMEMF];

    int t = threadIdx.x;
    if (t < 64) s_rows[t] = lists[p * B_ + start + min(t, nr - 1)];
    __syncthreads();

    int tx = t & 15, ty = t >> 4, ty4 = ty * 4;
    int wave = t >> 6, lane = t & 63;

    const float* Ab  = mus      + (size_t)(p >> 1) * B_ * 256;
    const float* Lb  = logvars  + (size_t)(p >> 1) * B_ * 256;
    const float* w1p = hw1 + (size_t)p * 512 * 96;
    const float* g1p = gw1 + (size_t)p * 512 * 32;

    // ---------- phase 1: Y[64][128] = h @ [hw1 | gw1] ----------
    float acc[4][8];
#pragma unroll
    for (int m = 0; m < 4; ++m)
#pragma unroll
        for (int n = 0; n < 8; ++n) acc[m][n] = 0.f;

    float* sA = smem;          // 64*44  = 2816
    float* sW = smem + 2816;   // 32*132 = 4224 -> 7040
    int arow = t >> 2, ac = (t & 3) * 8;

    for (int kt = 0; kt < 16; ++kt) {
        int k0 = kt * 32;
        const float* srcb = (k0 < 256) ? Ab : Lb;
        int koff = k0 & 255;
        {   // A tile: 64 x 32
            const float* g = srcb + (size_t)s_rows[arow] * 256 + koff + ac;
            float4 v0 = *(const float4*)g;
            float4 v1 = *(const float4*)(g + 4);
            *(float4*)(sA + arow * SA1 + ac)     = v0;
            *(float4*)(sA + arow * SA1 + ac + 4) = v1;
        }
        {   // W tile: 32 x (96 | 32)
            int k = t >> 3, c = (t & 7) * 12;
            const float* g = w1p + (size_t)(k0 + k) * 96 + c;
            float4 a0 = *(const float4*)g;
            float4 a1 = *(const float4*)(g + 4);
            float4 a2 = *(const float4*)(g + 8);
            float* d = sW + k * SW1 + c;
            *(float4*)d       = a0;
            *(float4*)(d + 4) = a1;
            *(float4*)(d + 8) = a2;
            int cg = (t & 7) * 4;
            *(float4*)(sW + k * SW1 + 96 + cg) =
                *(const float4*)(g1p + (size_t)(k0 + k) * 32 + cg);
        }
        __syncthreads();
#pragma unroll 4
        for (int kk = 0; kk < 32; ++kk) {
            float a0 = sA[(ty4 + 0) * SA1 + kk];
            float a1 = sA[(ty4 + 1) * SA1 + kk];
            float a2 = sA[(ty4 + 2) * SA1 + kk];
            float a3 = sA[(ty4 + 3) * SA1 + kk];
            const float* wr = sW + kk * SW1 + tx * 8;
            float4 w0 = *(const float4*)wr;
            float4 w1 = *(const float4*)(wr + 4);
            float wv[8] = {w0.x, w0.y, w0.z, w0.w, w1.x, w1.y, w1.z, w1.w};
#pragma unroll
            for (int n = 0; n < 8; ++n) {
                acc[0][n] = fmaf(a0, wv[n], acc[0][n]);
                acc[1][n] = fmaf(a1, wv[n], acc[1][n]);
                acc[2][n] = fmaf(a2, wv[n], acc[2][n]);
                acc[3][n] = fmaf(a3, wv[n], acc[3][n]);
            }
        }
        __syncthreads();
    }

    // bias + write Y (stride SW1)
    float* Y = smem;   // 64*132 = 8448
#pragma unroll
    for (int m = 0; m < 4; ++m) {
        int row = ty4 + m;
#pragma unroll
        for (int n = 0; n < 8; ++n) {
            int c = tx * 8 + n;
            float bias = (c < 96) ? hb1[p * 96 + c] : gb1[p * 32 + (c - 96)];
            Y[row * SW1 + c] = acc[m][n] + bias;
        }
    }
    __syncthreads();

    // ---------- LN + gelu (h branch -> X1), gate branch fused ----------
    float* X1 = smem + 9600;   // 64*100 = 6400 -> 16000
    for (int r = wave; r < 64; r += 4) {
        float v1 = Y[r * SW1 + lane];
        float v2 = (lane < 32) ? Y[r * SW1 + 64 + lane] : 0.f;
        float mean = wred64(v1 + v2) * (1.f / 96.f);
        float d1 = v1 - mean, d2 = v2 - mean;
        float var = wred64(d1 * d1 + ((lane < 32) ? d2 * d2 : 0.f)) * (1.f / 96.f);
        float rs = rsqrtf(var + 1e-5f);
        {
            int c = lane;
            X1[r * SX + c] = gelu_f(d1 * rs * hg1[p * 96 + c] + hbe1[p * 96 + c]);
        }
        if (lane < 32) {
            int c = 64 + lane;
            X1[r * SX + c] = gelu_f(d2 * rs * hg1[p * 96 + c] + hbe1[p * 96 + c]);
        }
        // gate branch: LN over 32 cols, gelu, dot gw2, sigmoid
        int cg = lane & 31;
        float v3 = Y[r * SW1 + 96 + cg];
        float s3 = v3;
#pragma unroll
        for (int m2 = 16; m2; m2 >>= 1) s3 += __shfl_xor(s3, m2, 64);
        float mg = s3 * (1.f / 32.f);
        float d3 = v3 - mg;
        float sq3 = d3 * d3;
#pragma unroll
        for (int m2 = 16; m2; m2 >>= 1) sq3 += __shfl_xor(sq3, m2, 64);
        float rsg = rsqrtf(sq3 * (1.f / 32.f) + 1e-5f);
        float gv = gelu_f(d3 * rsg * gg1[p * 32 + cg] + gbe1[p * 32 + cg]) * gw2[p * 32 + cg];
#pragma unroll
        for (int m2 = 16; m2; m2 >>= 1) gv += __shfl_xor(gv, m2, 64);
        if (lane == 0 && r < nr)
            out2[p * B_ + s_rows[r]] = 1.f / (1.f + expf(-(gv + gb2[p])));
    }
    __syncthreads();

    // ---------- phase 2: Y2 = X1 @ hw2 ----------
    float* W2 = smem;   // 96*96 = 9216 (contiguous, conflict-free reads)
    {
        const float4* gsrc = (const float4*)(hw2 + (size_t)p * 9216);
        float4* dst = (float4*)W2;
        for (int j = t; j < 2304; j += 256) dst[j] = gsrc[j];
    }
    __syncthreads();

    float acc2[4][6];
#pragma unroll
    for (int m = 0; m < 4; ++m)
#pragma unroll
        for (int n = 0; n < 6; ++n) acc2[m][n] = 0.f;
#pragma unroll 4
    for (int k = 0; k < 96; ++k) {
        float a0 = X1[(ty4 + 0) * SX + k];
        float a1 = X1[(ty4 + 1) * SX + k];
        float a2 = X1[(ty4 + 2) * SX + k];
        float a3 = X1[(ty4 + 3) * SX + k];
        const float* wr = W2 + k * 96 + tx * 6;
#pragma unroll
        for (int n = 0; n < 6; ++n) {
            float w = wr[n];
            acc2[0][n] = fmaf(a0, w, acc2[0][n]);
            acc2[1][n] = fmaf(a1, w, acc2[1][n]);
            acc2[2][n] = fmaf(a2, w, acc2[2][n]);
            acc2[3][n] = fmaf(a3, w, acc2[3][n]);
        }
    }
    __syncthreads();

    float* Y2 = smem;  // 64*100 = 6400 (overwrites W2 after sync)
#pragma unroll
    for (int m = 0; m < 4; ++m) {
        int row = ty4 + m;
#pragma unroll
        for (int n = 0; n < 6; ++n) {
            int c = tx * 6 + n;
            Y2[row * SX + c] = acc2[m][n] + hb2[p * 96 + c];
        }
    }
    __syncthreads();

    // LN2 + gelu in place -> X2
    for (int r = wave; r < 64; r += 4) {
        float v1 = Y2[r * SX + lane];
        float v2 = (lane < 32) ? Y2[r * SX + 64 + lane] : 0.f;
        float mean = wred64(v1 + v2) * (1.f / 96.f);
        float d1 = v1 - mean, d2 = v2 - mean;
        float var = wred64(d1 * d1 + ((lane < 32) ? d2 * d2 : 0.f)) * (1.f / 96.f);
        float rs = rsqrtf(var + 1e-5f);
        Y2[r * SX + lane] = gelu_f(d1 * rs * hg2[p * 96 + lane] + hbe2[p * 96 + lane]);
        if (lane < 32) {
            int c = 64 + lane;
            Y2[r * SX + c] = gelu_f(d2 * rs * hg2[p * 96 + c] + hbe2[p * 96 + c]);
        }
    }
    __syncthreads();

    // ---------- phase 3: out = X2 @ hw3 (+bias, clip, masked store) ----------
    float* X2 = smem;          // [0, 6400)
    float* W3 = smem + 6400;   // 96*132 = 12672 -> 19072
    const float* w3p = hw3 + (size_t)p * 96 * 512;

    for (int ch = 0; ch < 4; ++ch) {
        __syncthreads();
        for (int j = t; j < 3072; j += 256) {
            int k = j >> 5, c4 = (j & 31) * 4;
            *(float4*)(W3 + k * SW1 + c4) =
                *(const float4*)(w3p + (size_t)k * 512 + ch * 128 + c4);
        }
        __syncthreads();

        float acc3[4][8];
#pragma unroll
        for (int m = 0; m < 4; ++m)
#pragma unroll
            for (int n = 0; n < 8; ++n) acc3[m][n] = 0.f;
#pragma unroll 4
        for (int k = 0; k < 96; ++k) {
            float a0 = X2[(ty4 + 0) * SX + k];
            float a1 = X2[(ty4 + 1) * SX + k];
            float a2 = X2[(ty4 + 2) * SX + k];
            float a3 = X2[(ty4 + 3) * SX + k];
            const float* wr = W3 + k * SW1 + tx * 8;
            float4 w0 = *(const float4*)wr;
            float4 w1 = *(const float4*)(wr + 4);
            float wv[8] = {w0.x, w0.y, w0.z, w0.w, w1.x, w1.y, w1.z, w1.w};
#pragma unroll
            for (int n = 0; n < 8; ++n) {
                acc3[0][n] = fmaf(a0, wv[n], acc3[0][n]);
                acc3[1][n] = fmaf(a1, wv[n], acc3[1][n]);
                acc3[2][n] = fmaf(a2, wv[n], acc3[2][n]);
                acc3[3][n] = fmaf(a3, wv[n], acc3[3][n]);
            }
        }

#pragma unroll
        for (int m = 0; m < 4; ++m) {
            int row = ty4 + m;
            if (row < nr) {
                int b = s_rows[row];
                size_t rb = ((size_t)(p * B_ + b)) * 256;
                int c = ch * 128 + tx * 8;
                float o[8];
#pragma unroll
                for (int n = 0; n < 8; ++n) o[n] = acc3[m][n] + hb3[p * 512 + c + n];
                if (ch < 2) {
                    *(float4*)(out0 + rb + c)     = make_float4(o[0], o[1], o[2], o[3]);
                    *(float4*)(out0 + rb + c + 4) = make_float4(o[4], o[5], o[6], o[7]);
                } else {
#pragma unroll
                    for (int n = 0; n < 8; ++n) o[n] = fminf(fmaxf(o[n], -6.f), 2.f);
                    size_t cc = rb + (c - 256);
                    *(float4*)(out1 + cc)     = make_float4(o[0], o[1], o[2], o[3]);
                    *(float4*)(out1 + cc + 4) = make_float4(o[4], o[5], o[6], o[7]);
                }
            }
        }
    }
}

extern "C" void kernel_launch(void* const* d_in, const int* in_sizes, int n_in,
                              void* d_out, int out_size, void* d_ws, size_t ws_size,
                              hipStream_t stream)
{
    (void)in_sizes; (void)n_in; (void)out_size; (void)ws_size;

    const float* mus     = (const float*)d_in[0];
    const float* logvars = (const float*)d_in[1];
    const int*   mask    = (const int*)d_in[2];   // numpy bool -> int32 per harness
    const float* hw1  = (const float*)d_in[3];
    const float* hb1  = (const float*)d_in[4];
    const float* hg1  = (const float*)d_in[5];
    const float* hbe1 = (const float*)d_in[6];
    const float* hw2  = (const float*)d_in[7];
    const float* hb2  = (const float*)d_in[8];
    const float* hg2  = (const float*)d_in[9];
    const float* hbe2 = (const float*)d_in[10];
    const float* hw3  = (const float*)d_in[11];
    const float* hb3  = (const float*)d_in[12];
    const float* gw1  = (const float*)d_in[13];
    const float* gb1  = (const float*)d_in[14];
    const float* gg1  = (const float*)d_in[15];
    const float* gbe1 = (const float*)d_in[16];
    const float* gw2  = (const float*)d_in[17];
    const float* gb2  = (const float*)d_in[18];

    float* out0 = (float*)d_out;
    float* out1 = out0 + (size_t)NP * B_ * 256;
    float* out2 = out1 + (size_t)NP * B_ * 256;

    int* counts = (int*)d_ws;
    int* lists  = counts + 64;

    hipMemsetAsync(d_ws, 0, 64 * sizeof(int), stream);
    k_mask<<<dim3(NP * 256), dim3(256), 0, stream>>>(mask, out0, out1, out2, counts, lists);
    k_main<<<dim3(NP * 256), dim3(256), 0, stream>>>(
        mus, logvars, hw1, hb1, hg1, hbe1, hw2, hb2, hg2, hbe2, hw3, hb3,
        gw1, gb1, gg1, gbe1, gw2, gb2, counts, lists, out0, out1, out2);
}